// Round 6
// baseline (147.033 us; speedup 1.0000x reference)
//
#include <hip/hip_runtime.h>
#include <hip/hip_bf16.h>

#define NN 1024
#define LN_EPS 1e-5f

typedef __bf16 bf16x8 __attribute__((ext_vector_type(8)));
typedef float floatx16 __attribute__((ext_vector_type(16)));
typedef float floatx4 __attribute__((ext_vector_type(4)));
typedef float floatx2 __attribute__((ext_vector_type(2)));

__device__ __forceinline__ void load_lds16(const float* g, float* l) {
    __builtin_amdgcn_global_load_lds(
        (const __attribute__((address_space(1))) void*)g,
        (__attribute__((address_space(3))) void*)l, 16, 0, 0);
}

// Kernel 1 (blocks 0..1023, 256 thr): per-node precompute, 4 d-slices/wave.
//   Ap[i][h] = emb[i]·W1[:64,h] + b1[h]     (row-major [1024][64])
//   Bp[j][h] = emb[j]·W1[64:,h]             (row-major [1024][64])
//   sumA/sumB = row sums (LN1 mean is linear in A,B)
// Block 1024: pack W2^T into 32x32x16 MFMA A-fragment order (bf16).
__global__ __launch_bounds__(256) void precompute_ab(
    const float* __restrict__ emb, const float* __restrict__ W1,
    const float* __restrict__ b1, const float* __restrict__ W2,
    float* __restrict__ Ap, float* __restrict__ Bp,
    float* __restrict__ sumA, float* __restrict__ sumB,
    __bf16* __restrict__ Wf) {
    if (blockIdx.x == 1024) {
        // A-frag for mfma_f32_32x32x16_bf16: lane l holds A[m][k], m=l&31,
        // k = s*16 + (l>>5)*8 + t.  A = W2^T: A[m=h'][k] = W2[k][h'].
        int tid = threadIdx.x;
        if (tid >= 64) return;
        int m_l = tid & 31, kg = tid >> 5;
#pragma unroll
        for (int mt = 0; mt < 2; mt++)
#pragma unroll
            for (int s = 0; s < 4; s++) {
                bf16x8 f;
#pragma unroll
                for (int t = 0; t < 8; t++) {
                    int k = s * 16 + kg * 8 + t;
                    f[t] = (__bf16)W2[k * 64 + mt * 32 + m_l];
                }
                *(bf16x8*)&Wf[((mt * 4 + s) * 64 + tid) * 8] = f;
            }
        return;
    }
    __shared__ __align__(16) float e[64];
    __shared__ float pA[4][64], pB[4][64];
    int i = blockIdx.x;
    int h = threadIdx.x & 63, q = threadIdx.x >> 6;
    if (threadIdx.x < 64) e[h] = emb[i * 64 + h];
    __syncthreads();
    float a = 0.f, b = 0.f;
#pragma unroll
    for (int dd = 0; dd < 16; dd++) {
        int d = q * 16 + dd;
        a = fmaf(e[d], W1[d * 64 + h], a);
        b = fmaf(e[d], W1[(64 + d) * 64 + h], b);
    }
    pA[q][h] = a;
    pB[q][h] = b;
    __syncthreads();
    if (threadIdx.x < 64) {
        float ra = pA[0][h] + pA[1][h] + pA[2][h] + pA[3][h] + b1[h];
        float rb = pB[0][h] + pB[1][h] + pB[2][h] + pB[3][h];
        Ap[i * 64 + h] = ra;
        Bp[i * 64 + h] = rb;
#pragma unroll
        for (int off = 1; off < 64; off <<= 1) {
            ra += __shfl_xor(ra, off);
            rb += __shfl_xor(rb, off);
        }
        if (h == 0) { sumA[i] = ra; sumB[i] = rb; }
    }
}

// Kernel 2: fused pair-MLP (r5 verified structure; constants moved DS->VMEM).
// Block = 256 thr = 4 waves; block b: i = b>>3, j-tile = (b&7)*128.
// Wave w owns 32 pairs p = w*32 + (lane&31); kg2 = lane>>5 = h-dim half.
// ONLY Bt lives in LDS (32 KB -> 5 blocks/CU). All block-uniform constants
// (A-row, g1, be1, b2, g2, be2, W3) are read directly from global: broadcast
// dwordx4, 2 cache lines/wave, L1-resident -- offloads the congested per-CU
// LDS pipe (~78 -> ~22 DS ops/lane) onto the idle VMEM pipe.
__global__ __launch_bounds__(256, 5) void fused(
    const float* __restrict__ Ap, const float* __restrict__ Bp, const __bf16* __restrict__ Wf,
    const float* __restrict__ sumA, const float* __restrict__ sumB,
    const float* __restrict__ g1, const float* __restrict__ be1, const float* __restrict__ b2,
    const float* __restrict__ g2, const float* __restrict__ be2, const float* __restrict__ W3,
    const float* __restrict__ b3, const float* __restrict__ mask, float* __restrict__ out) {
    __shared__ __align__(16) float Bt[128 * 64];   // 32 KB swizzled f32 tile (exactly)

    int tid = threadIdx.x;
    int wave = tid >> 6, lane = tid & 63;
    int i = blockIdx.x >> 3;
    int j0 = (blockIdx.x & 7) * 128;

    // ---- stage Bt: wave's rows wave*32..+31; chunk swizzle
    // cs = (cp&8) | ((cp&7) ^ (row&7))  (involution; read uses same formula) ----
    {
        int cp = lane & 15;
#pragma unroll
        for (int o = 0; o < 8; o++) {
            int rr = wave * 32 + o * 4 + (lane >> 4);
            int cs = (cp & 8) | ((cp & 7) ^ (rr & 7));
            load_lds16(Bp + (j0 + rr) * 64 + cs * 4, Bt + (wave * 8 + o) * 256);
        }
    }
    __syncthreads();   // drains vmcnt(0): staging complete

    int m_l = lane & 31, kg2 = lane >> 5;
    int myp = wave * 32 + m_l;
    int myj = j0 + myp;

    float sBj = sumB[myj];               // coalesced
    float sAi = sumA[i];                 // uniform -> s_load
    float b3v = b3[0];                   // uniform -> s_load

    // ---- gr[s][q] = Bp[myj][s*16 + kg2*8 + q*4 ..+4] (swizzled b128 reads) ----
    floatx4 gr[4][2];
    const float* trow = Bt + myp * 64;
#pragma unroll
    for (int s = 0; s < 4; s++)
#pragma unroll
        for (int q = 0; q < 2; q++) {
            int c = s * 4 + kg2 * 2 + q;
            int sp = (c & 8) | ((c & 7) ^ (myp & 7));
            gr[s][q] = *(const floatx4*)(trow + sp * 4);
        }

    // ---- pass 1: x = a + b kept in regs; sum of squares; gr dies here ----
    const float* arow = Ap + i * 64 + kg2 * 8;     // global, L1-broadcast
    floatx4 x[4][2];
    floatx2 qv0 = {0.f, 0.f}, qv1 = {0.f, 0.f};
#pragma unroll
    for (int s = 0; s < 4; s++)
#pragma unroll
        for (int q = 0; q < 2; q++) {
            floatx4 a4 = *(const floatx4*)(arow + s * 16 + q * 4);
            floatx4 v = gr[s][q] + a4;            // 2x v_pk_add_f32
            x[s][q] = v;
            floatx2 vl = {v[0], v[1]}, vh = {v[2], v[3]};
            qv0 += vl * vl;                        // v_pk_fma_f32
            qv1 += vh * vh;
        }
    floatx2 qv = qv0 + qv1;
    float sq = qv[0] + qv[1];
    sq += __shfl_xor(sq, 32);            // partner lane holds other 32 h-elems

    float m1 = (sAi + sBj) * 0.015625f;
    float var1 = fmaf(m1, -m1, sq * 0.015625f);
    float rs1 = rsqrtf(var1 + LN_EPS);
    float o1 = -m1 * rs1;
    floatx2 p1v = {rs1, rs1}, o1v = {o1, o1};

    // ---- W2^T fragments (loaded after gr dies; L2-hot coalesced) ----
    bf16x8 afragW[2][4];
#pragma unroll
    for (int mt = 0; mt < 2; mt++)
#pragma unroll
        for (int s = 0; s < 4; s++)
            afragW[mt][s] = *(const bf16x8*)&Wf[((mt * 4 + s) * 64 + lane) * 8];

    // ---- acc init = b2 rows (global broadcast; MFMA accumulates on top) ----
    floatx16 acc0, acc1;
#pragma unroll
    for (int q = 0; q < 4; q++) {
        floatx4 b0 = *(const floatx4*)&b2[q * 8 + kg2 * 4];
        floatx4 b1q = *(const floatx4*)&b2[32 + q * 8 + kg2 * 4];
#pragma unroll
        for (int e2 = 0; e2 < 4; e2++) { acc0[q * 4 + e2] = b0[e2]; acc1[q * 4 + e2] = b1q[e2]; }
    }

    // ---- pass 2: LN1+ReLU on x -> bf16 B-frag, MFMA 32x32x16 ----
    const float* g1p = g1 + kg2 * 8;
    const float* e1p = be1 + kg2 * 8;
#pragma unroll
    for (int s = 0; s < 4; s++) {
        bf16x8 bh;
#pragma unroll
        for (int q = 0; q < 2; q++) {
            floatx4 gq = *(const floatx4*)(g1p + s * 16 + q * 4);
            floatx4 eq = *(const floatx4*)(e1p + s * 16 + q * 4);
#pragma unroll
            for (int t2 = 0; t2 < 2; t2++) {
                floatx2 xx = {x[s][q][2 * t2], x[s][q][2 * t2 + 1]};
                floatx2 xn = xx * p1v + o1v;                       // v_pk_fma_f32
                floatx2 y = xn * (floatx2){gq[2 * t2], gq[2 * t2 + 1]} +
                            (floatx2){eq[2 * t2], eq[2 * t2 + 1]};
                y = __builtin_elementwise_max(y, (floatx2){0.f, 0.f});
                bh[q * 4 + 2 * t2] = (__bf16)y[0];
                bh[q * 4 + 2 * t2 + 1] = (__bf16)y[1];
            }
        }
        acc0 = __builtin_amdgcn_mfma_f32_32x32x16_bf16(afragW[0][s], bh, acc0, 0, 0, 0);
        acc1 = __builtin_amdgcn_mfma_f32_32x32x16_bf16(afragW[1][s], bh, acc1, 0, 0, 0);
    }

    // ---- Epilogue: LN2, ReLU, dot W3, mask.  C 32x32 layout:
    // col = lane&31 (pair), row = (reg&3)+8*(reg>>2)+4*kg2 (+mt*32); b2 in acc.
    floatx2 s2v = {0.f, 0.f}, q2v = {0.f, 0.f};
#pragma unroll
    for (int mt = 0; mt < 2; mt++) {
        floatx16& A = mt ? acc1 : acc0;
#pragma unroll
        for (int q = 0; q < 4; q++) {
            floatx2 vlo = {A[q * 4 + 0], A[q * 4 + 1]};
            floatx2 vhi = {A[q * 4 + 2], A[q * 4 + 3]};
            s2v += vlo; s2v += vhi;              // v_pk_add_f32
            q2v += vlo * vlo; q2v += vhi * vhi;  // v_pk_fma_f32
        }
    }
    float s2 = s2v[0] + s2v[1], q2 = q2v[0] + q2v[1];
    s2 += __shfl_xor(s2, 32);
    q2 += __shfl_xor(q2, 32);
    float m2 = s2 * 0.015625f;
    float var2 = fmaf(m2, -m2, q2 * 0.015625f);
    float rs2 = rsqrtf(var2 + LN_EPS);
    floatx2 p2 = {rs2, rs2};
    float o2s = -m2 * rs2;
    floatx2 o2 = {o2s, o2s};

    floatx2 scv = {0.f, 0.f};
#pragma unroll
    for (int mt = 0; mt < 2; mt++) {
        floatx16& A = mt ? acc1 : acc0;
#pragma unroll
        for (int q = 0; q < 4; q++) {
            int r0 = mt * 32 + q * 8 + kg2 * 4;
            floatx4 gq = *(const floatx4*)&g2[r0];
            floatx4 eq = *(const floatx4*)&be2[r0];
            floatx4 wq = *(const floatx4*)&W3[r0];
            floatx2 vlo = {A[q * 4 + 0], A[q * 4 + 1]};
            floatx2 vhi = {A[q * 4 + 2], A[q * 4 + 3]};
            floatx2 xlo = vlo * p2 + o2;
            floatx2 xhi = vhi * p2 + o2;
            floatx2 ylo = xlo * (floatx2){gq[0], gq[1]} + (floatx2){eq[0], eq[1]};
            floatx2 yhi = xhi * (floatx2){gq[2], gq[3]} + (floatx2){eq[2], eq[3]};
            ylo = __builtin_elementwise_max(ylo, (floatx2){0.f, 0.f});
            yhi = __builtin_elementwise_max(yhi, (floatx2){0.f, 0.f});
            scv += ylo * (floatx2){wq[0], wq[1]};
            scv += yhi * (floatx2){wq[2], wq[3]};
        }
    }
    float sc = scv[0] + scv[1];
    sc += __shfl_xor(sc, 32);

    if (kg2 == 0) {
        int p = i * NN + myj;
        out[p] = (i == myj) ? 0.f : (sc + b3v) * mask[p];
    }
}

extern "C" void kernel_launch(void* const* d_in, const int* in_sizes, int n_in,
                              void* d_out, int out_size, void* d_ws, size_t ws_size,
                              hipStream_t stream) {
    const float* emb = (const float*)d_in[0];
    const float* mask = (const float*)d_in[1];
    const float* W1 = (const float*)d_in[2];
    const float* b1 = (const float*)d_in[3];
    const float* g1 = (const float*)d_in[4];
    const float* be1 = (const float*)d_in[5];
    const float* W2 = (const float*)d_in[6];
    const float* b2 = (const float*)d_in[7];
    const float* g2 = (const float*)d_in[8];
    const float* be2 = (const float*)d_in[9];
    const float* W3 = (const float*)d_in[10];
    const float* b3 = (const float*)d_in[11];
    float* out = (float*)d_out;

    float* Ap = (float*)d_ws;                 // 1024*64 f32 = 256 KB
    float* Bp = Ap + 1024 * 64;               // 1024*64 f32 = 256 KB (row-major [j][h])
    float* sA = Bp + 1024 * 64;               // 1024 f32
    float* sB = sA + 1024;                    // 1024 f32
    __bf16* Wf = (__bf16*)(sB + 1024);        // 4096 bf16 = 8 KB

    precompute_ab<<<1025, 256, 0, stream>>>(emb, W1, b1, W2, Ap, Bp, sA, sB, Wf);
    fused<<<8192, 256, 0, stream>>>(Ap, Bp, Wf, sA, sB,
                                    g1, be1, b2, g2, be2, W3, b3, mask, out);
}

// Round 7
// 106.521 us; speedup vs baseline: 1.3803x; 1.3803x over previous
//
#include <hip/hip_runtime.h>
#include <hip/hip_bf16.h>

#define NN 1024
#define LN_EPS 1e-5f

typedef __bf16 bf16x8 __attribute__((ext_vector_type(8)));
typedef float floatx16 __attribute__((ext_vector_type(16)));
typedef float floatx4 __attribute__((ext_vector_type(4)));
typedef float floatx2 __attribute__((ext_vector_type(2)));

__device__ __forceinline__ void load_lds16(const float* g, float* l) {
    __builtin_amdgcn_global_load_lds(
        (const __attribute__((address_space(1))) void*)g,
        (__attribute__((address_space(3))) void*)l, 16, 0, 0);
}

// Kernel 1 (blocks 0..1023, 256 thr): per-node precompute, 4 d-slices/wave.
//   Ap[i][h] = emb[i]·W1[:64,h] + b1[h]     (row-major [1024][64])
//   Bp[j][h] = emb[j]·W1[64:,h]             (row-major [1024][64])
//   sumA/sumB = row sums (LN1 mean is linear in A,B)
// Block 1024: pack W2^T into 32x32x16 MFMA A-fragment order (bf16).
__global__ __launch_bounds__(256) void precompute_ab(
    const float* __restrict__ emb, const float* __restrict__ W1,
    const float* __restrict__ b1, const float* __restrict__ W2,
    float* __restrict__ Ap, float* __restrict__ Bp,
    float* __restrict__ sumA, float* __restrict__ sumB,
    __bf16* __restrict__ Wf) {
    if (blockIdx.x == 1024) {
        // A-frag for mfma_f32_32x32x16_bf16: lane l holds A[m][k], m=l&31,
        // k = s*16 + (l>>5)*8 + t.  A = W2^T: A[m=h'][k] = W2[k][h'].
        int tid = threadIdx.x;
        if (tid >= 64) return;
        int m_l = tid & 31, kg = tid >> 5;
#pragma unroll
        for (int mt = 0; mt < 2; mt++)
#pragma unroll
            for (int s = 0; s < 4; s++) {
                bf16x8 f;
#pragma unroll
                for (int t = 0; t < 8; t++) {
                    int k = s * 16 + kg * 8 + t;
                    f[t] = (__bf16)W2[k * 64 + mt * 32 + m_l];
                }
                *(bf16x8*)&Wf[((mt * 4 + s) * 64 + tid) * 8] = f;
            }
        return;
    }
    __shared__ __align__(16) float e[64];
    __shared__ float pA[4][64], pB[4][64];
    int i = blockIdx.x;
    int h = threadIdx.x & 63, q = threadIdx.x >> 6;
    if (threadIdx.x < 64) e[h] = emb[i * 64 + h];
    __syncthreads();
    float a = 0.f, b = 0.f;
#pragma unroll
    for (int dd = 0; dd < 16; dd++) {
        int d = q * 16 + dd;
        a = fmaf(e[d], W1[d * 64 + h], a);
        b = fmaf(e[d], W1[(64 + d) * 64 + h], b);
    }
    pA[q][h] = a;
    pB[q][h] = b;
    __syncthreads();
    if (threadIdx.x < 64) {
        float ra = pA[0][h] + pA[1][h] + pA[2][h] + pA[3][h] + b1[h];
        float rb = pB[0][h] + pB[1][h] + pB[2][h] + pB[3][h];
        Ap[i * 64 + h] = ra;
        Bp[i * 64 + h] = rb;
#pragma unroll
        for (int off = 1; off < 64; off <<= 1) {
            ra += __shfl_xor(ra, off);
            rb += __shfl_xor(rb, off);
        }
        if (h == 0) { sumA[i] = ra; sumB[i] = rb; }
    }
}

// Kernel 2: fused pair-MLP, wave-per-i tiling. Block = 256 thr = 4 waves.
// Block b: j-tile = (b&31)*32 (32 rows, shared by ALL 4 waves); i = (b>>5)*4
// + wave (each wave its own i). Per-pair math identical to r5 (verified):
// lane pair p = lane&31, kg2 = lane>>5 = h-dim half; gr swizzled b128 reads;
// f32 sum(x^2) LN1; h1 -> bf16 B-frag -> mfma_f32_32x32x16_bf16; b2 in acc.
// Deltas vs r5: Bt 32KB -> 8KB (4x less staging traffic, 4x fewer stage ops,
// LDS ~10.8KB -> ~6 blocks/CU resident); constants + A-rows stay in LDS
// (r6 proved VMEM broadcast is latency-poison).
__global__ __launch_bounds__(256, 5) void fused(
    const float* __restrict__ Ap, const float* __restrict__ Bp, const __bf16* __restrict__ Wf,
    const float* __restrict__ sumA, const float* __restrict__ sumB,
    const float* __restrict__ g1, const float* __restrict__ be1, const float* __restrict__ b2,
    const float* __restrict__ g2, const float* __restrict__ be2, const float* __restrict__ W3,
    const float* __restrict__ b3, const float* __restrict__ mask, float* __restrict__ out) {
    __shared__ __align__(16) float Bt[32 * 64];    // 8 KB swizzled f32 j-tile
    __shared__ __align__(16) float As[4 * 64];     // the block's 4 A-rows
    __shared__ __align__(16) float G1s[64], E1s[64], B2s[64], G2s[64], E2s[64], W3s[64];

    int tid = threadIdx.x;
    int wave = tid >> 6, lane = tid & 63;
    int ig = blockIdx.x >> 5;            // i-group: rows ig*4 .. +3
    int j0 = (blockIdx.x & 31) * 32;
    int i = ig * 4 + wave;               // this wave's i

    // ---- stage Bt (8 KB): wave w stages rows w*8..w*8+7, 2 ops of 1KB.
    // chunk swizzle cs = (cp&8) | ((cp&7) ^ (row&7))  (involution) ----
    {
        int cp = lane & 15;
#pragma unroll
        for (int o = 0; o < 2; o++) {
            int rr = wave * 8 + o * 4 + (lane >> 4);
            int cs = (cp & 8) | ((cp & 7) ^ (rr & 7));
            load_lds16(Bp + (j0 + rr) * 64 + cs * 4, Bt + (wave * 2 + o) * 256);
        }
        if (wave == 0)   // 4 A-rows = 1 KB in one op (dest = As + lane*16)
            load_lds16(Ap + ig * 256 + lane * 4, As);
    }
    if (tid < 64) {
        G1s[tid] = g1[tid]; E1s[tid] = be1[tid]; B2s[tid] = b2[tid];
        G2s[tid] = g2[tid]; E2s[tid] = be2[tid]; W3s[tid] = W3[tid];
    }
    __syncthreads();   // drains vmcnt(0): all staging complete

    int m_l = lane & 31, kg2 = lane >> 5;
    int myj = j0 + m_l;

    float sBj = sumB[myj];               // coalesced 128B
    float sAi = sumA[i];                 // wave-uniform broadcast
    float b3v = b3[0];

    // ---- gr[s][q] = Bp[myj][s*16 + kg2*8 + q*4 ..+4] (swizzled b128 reads) ----
    floatx4 gr[4][2];
    const float* trow = Bt + m_l * 64;
#pragma unroll
    for (int s = 0; s < 4; s++)
#pragma unroll
        for (int q = 0; q < 2; q++) {
            int c = s * 4 + kg2 * 2 + q;
            int sp = (c & 8) | ((c & 7) ^ (m_l & 7));
            gr[s][q] = *(const floatx4*)(trow + sp * 4);
        }

    // ---- pass 1: x = a + b kept in regs; sum of squares; gr dies here ----
    const float* arow = As + wave * 64 + kg2 * 8;   // LDS broadcast (2 addrs/wave)
    floatx4 x[4][2];
    floatx2 qv0 = {0.f, 0.f}, qv1 = {0.f, 0.f};
#pragma unroll
    for (int s = 0; s < 4; s++)
#pragma unroll
        for (int q = 0; q < 2; q++) {
            floatx4 a4 = *(const floatx4*)(arow + s * 16 + q * 4);
            floatx4 v = gr[s][q] + a4;            // 2x v_pk_add_f32
            x[s][q] = v;
            floatx2 vl = {v[0], v[1]}, vh = {v[2], v[3]};
            qv0 += vl * vl;                        // v_pk_fma_f32
            qv1 += vh * vh;
        }
    floatx2 qv = qv0 + qv1;
    float sq = qv[0] + qv[1];
    sq += __shfl_xor(sq, 32);            // partner lane holds other 32 h-elems

    float m1 = (sAi + sBj) * 0.015625f;
    float var1 = fmaf(m1, -m1, sq * 0.015625f);
    float rs1 = rsqrtf(var1 + LN_EPS);
    float o1 = -m1 * rs1;
    floatx2 p1v = {rs1, rs1}, o1v = {o1, o1};

    // ---- W2^T fragments (loaded after gr dies; L2-hot coalesced) ----
    bf16x8 afragW[2][4];
#pragma unroll
    for (int mt = 0; mt < 2; mt++)
#pragma unroll
        for (int s = 0; s < 4; s++)
            afragW[mt][s] = *(const bf16x8*)&Wf[((mt * 4 + s) * 64 + lane) * 8];

    // ---- acc init = b2 rows (LDS broadcast; MFMA accumulates on top) ----
    floatx16 acc0, acc1;
#pragma unroll
    for (int q = 0; q < 4; q++) {
        floatx4 b0 = *(const floatx4*)&B2s[q * 8 + kg2 * 4];
        floatx4 b1q = *(const floatx4*)&B2s[32 + q * 8 + kg2 * 4];
#pragma unroll
        for (int e2 = 0; e2 < 4; e2++) { acc0[q * 4 + e2] = b0[e2]; acc1[q * 4 + e2] = b1q[e2]; }
    }

    // ---- pass 2: LN1+ReLU on x -> bf16 B-frag, MFMA 32x32x16 ----
#pragma unroll
    for (int s = 0; s < 4; s++) {
        bf16x8 bh;
#pragma unroll
        for (int q = 0; q < 2; q++) {
            floatx4 gq = *(const floatx4*)&G1s[s * 16 + kg2 * 8 + q * 4];
            floatx4 eq = *(const floatx4*)&E1s[s * 16 + kg2 * 8 + q * 4];
#pragma unroll
            for (int t2 = 0; t2 < 2; t2++) {
                floatx2 xx = {x[s][q][2 * t2], x[s][q][2 * t2 + 1]};
                floatx2 xn = xx * p1v + o1v;                       // v_pk_fma_f32
                floatx2 y = xn * (floatx2){gq[2 * t2], gq[2 * t2 + 1]} +
                            (floatx2){eq[2 * t2], eq[2 * t2 + 1]};
                y = __builtin_elementwise_max(y, (floatx2){0.f, 0.f});
                bh[q * 4 + 2 * t2] = (__bf16)y[0];
                bh[q * 4 + 2 * t2 + 1] = (__bf16)y[1];
            }
        }
        acc0 = __builtin_amdgcn_mfma_f32_32x32x16_bf16(afragW[0][s], bh, acc0, 0, 0, 0);
        acc1 = __builtin_amdgcn_mfma_f32_32x32x16_bf16(afragW[1][s], bh, acc1, 0, 0, 0);
    }

    // ---- Epilogue: LN2, ReLU, dot W3, mask.  C 32x32 layout:
    // col = lane&31 (pair), row = (reg&3)+8*(reg>>2)+4*kg2 (+mt*32); b2 in acc.
    floatx2 s2v = {0.f, 0.f}, q2v = {0.f, 0.f};
#pragma unroll
    for (int mt = 0; mt < 2; mt++) {
        floatx16& A = mt ? acc1 : acc0;
#pragma unroll
        for (int q = 0; q < 4; q++) {
            floatx2 vlo = {A[q * 4 + 0], A[q * 4 + 1]};
            floatx2 vhi = {A[q * 4 + 2], A[q * 4 + 3]};
            s2v += vlo; s2v += vhi;              // v_pk_add_f32
            q2v += vlo * vlo; q2v += vhi * vhi;  // v_pk_fma_f32
        }
    }
    float s2 = s2v[0] + s2v[1], q2 = q2v[0] + q2v[1];
    s2 += __shfl_xor(s2, 32);
    q2 += __shfl_xor(q2, 32);
    float m2 = s2 * 0.015625f;
    float var2 = fmaf(m2, -m2, q2 * 0.015625f);
    float rs2 = rsqrtf(var2 + LN_EPS);
    floatx2 p2 = {rs2, rs2};
    float o2s = -m2 * rs2;
    floatx2 o2 = {o2s, o2s};

    floatx2 scv = {0.f, 0.f};
#pragma unroll
    for (int mt = 0; mt < 2; mt++) {
        floatx16& A = mt ? acc1 : acc0;
#pragma unroll
        for (int q = 0; q < 4; q++) {
            int r0 = mt * 32 + q * 8 + kg2 * 4;
            floatx4 gq = *(const floatx4*)&G2s[r0];
            floatx4 eq = *(const floatx4*)&E2s[r0];
            floatx4 wq = *(const floatx4*)&W3s[r0];
            floatx2 vlo = {A[q * 4 + 0], A[q * 4 + 1]};
            floatx2 vhi = {A[q * 4 + 2], A[q * 4 + 3]};
            floatx2 xlo = vlo * p2 + o2;
            floatx2 xhi = vhi * p2 + o2;
            floatx2 ylo = xlo * (floatx2){gq[0], gq[1]} + (floatx2){eq[0], eq[1]};
            floatx2 yhi = xhi * (floatx2){gq[2], gq[3]} + (floatx2){eq[2], eq[3]};
            ylo = __builtin_elementwise_max(ylo, (floatx2){0.f, 0.f});
            yhi = __builtin_elementwise_max(yhi, (floatx2){0.f, 0.f});
            scv += ylo * (floatx2){wq[0], wq[1]};
            scv += yhi * (floatx2){wq[2], wq[3]};
        }
    }
    float sc = scv[0] + scv[1];
    sc += __shfl_xor(sc, 32);

    if (kg2 == 0) {
        int p = i * NN + myj;
        out[p] = (i == myj) ? 0.f : (sc + b3v) * mask[p];
    }
}

extern "C" void kernel_launch(void* const* d_in, const int* in_sizes, int n_in,
                              void* d_out, int out_size, void* d_ws, size_t ws_size,
                              hipStream_t stream) {
    const float* emb = (const float*)d_in[0];
    const float* mask = (const float*)d_in[1];
    const float* W1 = (const float*)d_in[2];
    const float* b1 = (const float*)d_in[3];
    const float* g1 = (const float*)d_in[4];
    const float* be1 = (const float*)d_in[5];
    const float* W2 = (const float*)d_in[6];
    const float* b2 = (const float*)d_in[7];
    const float* g2 = (const float*)d_in[8];
    const float* be2 = (const float*)d_in[9];
    const float* W3 = (const float*)d_in[10];
    const float* b3 = (const float*)d_in[11];
    float* out = (float*)d_out;

    float* Ap = (float*)d_ws;                 // 1024*64 f32 = 256 KB
    float* Bp = Ap + 1024 * 64;               // 1024*64 f32 = 256 KB (row-major [j][h])
    float* sA = Bp + 1024 * 64;               // 1024 f32
    float* sB = sA + 1024;                    // 1024 f32
    __bf16* Wf = (__bf16*)(sB + 1024);        // 4096 bf16 = 8 KB

    precompute_ab<<<1025, 256, 0, stream>>>(emb, W1, b1, W2, Ap, Bp, sA, sB, Wf);
    fused<<<8192, 256, 0, stream>>>(Ap, Bp, Wf, sA, sB,
                                    g1, be1, b2, g2, be2, W3, b3, mask, out);
}